// Round 5
// baseline (205.807 us; speedup 1.0000x reference)
//
#include <hip/hip_runtime.h>

// ---------------------------------------------------------------------------
// Causal single-head attention, B=64 T=512 C=768 H=72, fp32 in/out.
// cast_w: W -> wbt bf16 [3][80][768] (transposed, padded, Wq pre-scaled)
// proj:   fused QKV GEMM; W chunk-resident in LDS (3 x K=256, swizzled),
//         x A-frags straight from global fp32 -> bf16 in-register.
//         Outputs Qg/Kg [32768][104] bf16 (cols 72..103 zero),
//         Vt [64][80][512] bf16 (row 72 = ones).
// attn:   flash-style, no running max (R3 version, TK=64), denominator =
//         PV ones-column, XOR-swizzled lv, balanced 512-block grid.
// ---------------------------------------------------------------------------

typedef short bf16x8 __attribute__((ext_vector_type(8)));
typedef float f32x4 __attribute__((ext_vector_type(4)));

#define DEVI __device__ __forceinline__

DEVI unsigned f2bf(float f) {  // fp32 -> bf16 RNE (low 16 of result)
  unsigned u = __builtin_bit_cast(unsigned, f);
  return (u + 0x7fffu + ((u >> 16) & 1u)) >> 16;
}
DEVI unsigned pk2(float a, float b) { return f2bf(a) | (f2bf(b) << 16); }

DEVI bf16x8 pack8(float4 a, float4 c) {
  uint4 o = {pk2(a.x, a.y), pk2(a.z, a.w), pk2(c.x, c.y), pk2(c.z, c.w)};
  return __builtin_bit_cast(bf16x8, o);
}

DEVI void async16(void* lds, const void* g) {  // global->LDS, lane*16B
  __builtin_amdgcn_global_load_lds(
      (const __attribute__((address_space(1))) unsigned int*)g,
      (__attribute__((address_space(3))) unsigned int*)lds, 16, 0, 0);
}

// ---------------------------------------------------------------- cast_w ----
__global__ __launch_bounds__(256) void cast_w_k(const float* __restrict__ Wk,
                                                const float* __restrict__ Wq,
                                                const float* __restrict__ Wv,
                                                unsigned short* __restrict__ wbt) {
  __shared__ float ldsT[72][65];
  const int mat = blockIdx.x / 12, kc = blockIdx.x % 12;
  const float* W = (mat == 0) ? Wk : (mat == 1) ? Wq : Wv;
  const float sc = (mat == 1) ? 0.11785113019775793f : 1.0f;  // 72^-0.5 in q
  const float* src = W + kc * 64 * 72;
  for (int i = threadIdx.x; i < 1152; i += 256) {
    float4 d = *(const float4*)(src + i * 4);
    int e = i * 4;
    ldsT[e % 72][e / 72] = d.x;
    ldsT[(e + 1) % 72][(e + 1) / 72] = d.y;
    ldsT[(e + 2) % 72][(e + 2) / 72] = d.z;
    ldsT[(e + 3) % 72][(e + 3) / 72] = d.w;
  }
  __syncthreads();
  for (int c = threadIdx.x; c < 640; c += 256) {
    int h = c >> 3, kb = (c & 7) * 8;
    uint4 o = {0u, 0u, 0u, 0u};
    if (h < 72) {
      const float* rowp = &ldsT[h][kb];
      o.x = pk2(rowp[0] * sc, rowp[1] * sc);
      o.y = pk2(rowp[2] * sc, rowp[3] * sc);
      o.z = pk2(rowp[4] * sc, rowp[5] * sc);
      o.w = pk2(rowp[6] * sc, rowp[7] * sc);
    }
    *(uint4*)(wbt + ((size_t)mat * 80 + h) * 768 + kc * 64 + kb) = o;
  }
}

// ------------------------------------------------------------------ proj ----
// grid 256, 256 thr / 4 waves. M=128, N=240 (K|Q|V).
// W resident in LDS per K-chunk (256 cols, 120 KB, 32-block XOR swizzle);
// x A-frags loaded directly global->VGPR (fp32) and packed to bf16.
struct ProjSmem {
  union {
    short w[240 * 256];  // 122,880 B
    short t[80 * 136];   // V-transpose
  };
};

__global__ __launch_bounds__(256, 1) void proj_k(
    const float* __restrict__ x, const unsigned short* __restrict__ wbt,
    unsigned short* __restrict__ Kg, unsigned short* __restrict__ Qg,
    unsigned short* __restrict__ Vt) {
  __shared__ __align__(16) ProjSmem sm;
  const int row0 = blockIdx.x * 128;
  const int tid = threadIdx.x, wave = tid >> 6, lane = tid & 63;
  const int quad = lane >> 4, l16 = lane & 15;
  const int wr = wave * 32;

  f32x4 acc[2][15] = {};

  for (int kc = 0; kc < 3; ++kc) {
    const int kbase = kc * 256;
    // stage W chunk [240][256] bf16; inst = 2 rows; source block swizzled
#pragma unroll
    for (int j = 0; j < 30; ++j) {
      int inst = j * 4 + wave;  // 0..119
      int r = 2 * inst + (lane >> 5);
      int cb = lane & 31;
      async16(&sm.w[inst * 512],
              wbt + (size_t)r * 768 + kbase + ((cb ^ (r & 31)) * 8));
    }
    __syncthreads();
#pragma unroll
    for (int ks = 0; ks < 8; ++ks) {
      bf16x8 af[2];
#pragma unroll
      for (int mt = 0; mt < 2; ++mt) {
        const float* g = x + (size_t)(row0 + wr + mt * 16 + l16) * 768 +
                         kbase + ks * 32 + quad * 8;
        af[mt] = pack8(*(const float4*)g, *(const float4*)(g + 4));
      }
#pragma unroll
      for (int nt = 0; nt < 15; ++nt) {
        int row = nt * 16 + l16;
        bf16x8 bf = *(const bf16x8*)&sm.w[row * 256 +
                                          (((ks * 4 + quad) ^ (row & 31)) * 8)];
        acc[0][nt] = __builtin_amdgcn_mfma_f32_16x16x32_bf16(af[0], bf, acc[0][nt], 0, 0, 0);
        acc[1][nt] = __builtin_amdgcn_mfma_f32_16x16x32_bf16(af[1], bf, acc[1][nt], 0, 0, 0);
      }
    }
    __syncthreads();
  }

  // K (nt 0..4) / Q (nt 5..9): rows of 104, cols 72..103 zero.
#pragma unroll
  for (int gsel = 0; gsel < 2; ++gsel) {
    unsigned short* G = gsel ? Qg : Kg;
#pragma unroll
    for (int mt = 0; mt < 2; ++mt)
#pragma unroll
      for (int r = 0; r < 4; ++r) {
        size_t row = (size_t)row0 + wr + mt * 16 + quad * 4 + r;
        unsigned short* p = G + row * 104;
#pragma unroll
        for (int nt = 0; nt < 5; ++nt)
          p[nt * 16 + l16] = (unsigned short)f2bf(acc[mt][gsel * 5 + nt][r]);
        p[80 + l16] = 0;
        if (l16 < 8) p[96 + l16] = 0;
      }
  }
  // V (nt 10..14): transpose via LDS -> Vt [b][80][512], row 72 := ones.
#pragma unroll
  for (int mt = 0; mt < 2; ++mt)
#pragma unroll
    for (int nt = 0; nt < 5; ++nt)
#pragma unroll
      for (int r = 0; r < 4; ++r)
        sm.t[(nt * 16 + l16) * 136 + wr + mt * 16 + quad * 4 + r] =
            (short)f2bf(acc[mt][10 + nt][r]);
  __syncthreads();
  int b = blockIdx.x >> 2, t0 = (blockIdx.x & 3) * 128;
  const uint4 ones = {0x3F803F80u, 0x3F803F80u, 0x3F803F80u, 0x3F803F80u};
  for (int c = tid; c < 1280; c += 256) {
    int hr = c >> 4, tc = (c & 15) * 8;
    uint4 d = *(const uint4*)&sm.t[hr * 136 + tc];
    if (hr == 72) d = ones;
    *(uint4*)(Vt + ((size_t)b * 80 + hr) * 512 + t0 + tc) = d;
  }
}

// ------------------------------------------------------------------ attn ----
// R3 version: 512 blocks (balance-permuted), 4 waves, 16 Q-rows/wave, TK=64.
__global__ __launch_bounds__(256, 4) void attn_k(
    const unsigned short* __restrict__ Qg, const unsigned short* __restrict__ Kg,
    const unsigned short* __restrict__ Vt, float* __restrict__ out) {
  __shared__ __align__(16) short lk[64 * 104];    // stride 104: 2-way free
  __shared__ __align__(16) short lv[80 * 64];     // stride 64 + XOR swizzle
  __shared__ __align__(16) short lp[4][16 * 72];  // per-wave P, stride 72

  int idx = (blockIdx.x < 256) ? blockIdx.x : 767 - blockIdx.x;
  const int qb = 7 - (idx >> 6), b = idx & 63;
  const int tid = threadIdx.x, wave = tid >> 6, lane = tid & 63;
  const int quad = lane >> 4, l16 = lane & 15;
  const int lrow = lane >> 3, lcb = lane & 7;
  const int trow0 = qb * 64 + wave * 16;

  bf16x8 qf[3];
#pragma unroll
  for (int kt = 0; kt < 3; ++kt)
    qf[kt] = *(const bf16x8*)(Qg + ((size_t)b * 512 + trow0 + l16) * 104 + kt * 32 + quad * 8);

  f32x4 o[5] = {};

  for (int kb = 0; kb <= qb; ++kb) {
    const int s0 = kb * 64;
    const bool diag = (kb == qb);
    const int nact = diag ? (wave + 1) : 4;

#pragma unroll
    for (int j = 0; j < 4; ++j) {  // K tile: 64 x 104 = 13 KiB linear
      int inst = j * 4 + wave;
      if (inst < 13)
        async16(&lk[inst * 512], Kg + ((size_t)b * 512 + s0) * 104 + inst * 512 + lane * 8);
    }
    for (int j = wave; j < 10; j += 4) {  // V^T tile, swizzled source
      int r = j * 8 + lrow;
      async16(&lv[j * 512], Vt + ((size_t)b * 80 + r) * 512 + s0 + (lcb ^ lrow) * 8);
    }
    __syncthreads();

    f32x4 sacc[4] = {};
#pragma unroll
    for (int kt = 0; kt < 3; ++kt)
      for (int nt = 0; nt < nact; ++nt) {
        bf16x8 kf = *(const bf16x8*)&lk[(nt * 16 + l16) * 104 + kt * 32 + quad * 8];
        sacc[nt] = __builtin_amdgcn_mfma_f32_16x16x32_bf16(qf[kt], kf, sacc[nt], 0, 0, 0);
      }
    if (diag) {  // mask the straddling tile nt == wave
      int nt = wave;
#pragma unroll
      for (int r = 0; r < 4; ++r) {
        int t = trow0 + quad * 4 + r;
        if (s0 + nt * 16 + l16 > t) sacc[nt][r] = -1e30f;
      }
    }
    // p = exp(s) (no max subtraction), write to per-wave LDS in A-layout
#pragma unroll
    for (int nt = 0; nt < 4; ++nt)
#pragma unroll
      for (int r = 0; r < 4; ++r) {
        float p = (nt < nact) ? __expf(sacc[nt][r]) : 0.0f;
        lp[wave][(quad * 4 + r) * 72 + nt * 16 + l16] = (short)f2bf(p);
      }
    // O += P V^ (column 72 of V^ is ones -> denominator in o[4])
#pragma unroll
    for (int ks = 0; ks < 2; ++ks) {
      bf16x8 pf = *(const bf16x8*)&lp[wave][l16 * 72 + ks * 32 + quad * 8];
      const int pblk = ((ks << 2) | quad) ^ (l16 & 7);
#pragma unroll
      for (int nt = 0; nt < 5; ++nt) {
        bf16x8 vf = *(const bf16x8*)&lv[(nt * 16 + l16) * 64 + pblk * 8];
        o[nt] = __builtin_amdgcn_mfma_f32_16x16x32_bf16(pf, vf, o[nt], 0, 0, 0);
      }
    }
    __syncthreads();
  }

#pragma unroll
  for (int r = 0; r < 4; ++r) {
    float l = __shfl(o[4][r], (lane & 48) | 8, 64);
    float inv = 1.0f / l;
    size_t t = (size_t)b * 512 + trow0 + quad * 4 + r;
#pragma unroll
    for (int nt = 0; nt < 5; ++nt) {
      int h = nt * 16 + l16;
      if (h < 72) out[t * 72 + h] = o[nt][r] * inv;
    }
  }
}

// ---------------------------------------------------------------------------
extern "C" void kernel_launch(void* const* d_in, const int* in_sizes, int n_in,
                              void* d_out, int out_size, void* d_ws, size_t ws_size,
                              hipStream_t stream) {
  const float* x  = (const float*)d_in[0];
  const float* Wk = (const float*)d_in[1];
  const float* Wq = (const float*)d_in[2];
  const float* Wv = (const float*)d_in[3];
  float* out = (float*)d_out;

  char* ws = (char*)d_ws;
  unsigned short* Kg  = (unsigned short*)(ws);             // 6,815,744
  unsigned short* Qg  = (unsigned short*)(ws + 6815744);   // 6,815,744
  unsigned short* Vt  = (unsigned short*)(ws + 13631488);  // 5,242,880
  unsigned short* wbt = (unsigned short*)(ws + 18874368);  //   368,640

  cast_w_k<<<36, 256, 0, stream>>>(Wk, Wq, Wv, wbt);
  proj_k<<<256, 256, 0, stream>>>(x, wbt, Kg, Qg, Vt);
  attn_k<<<512, 256, 0, stream>>>(Qg, Kg, Vt, out);
}

// Round 6
// 192.976 us; speedup vs baseline: 1.0665x; 1.0665x over previous
//
#include <hip/hip_runtime.h>

// ---------------------------------------------------------------------------
// Causal single-head attention, B=64 T=512 C=768 H=72, fp32 in/out.
// cast_w: W -> wbt bf16 [3][80][768] (transposed, padded, Wq pre-scaled)
// proj:   fused QKV GEMM, M=64 grid 512 (2 blocks/CU), waves 2x2 over (M,N);
//         x cast fp32->bf16 in staging. Qg/Kg [32768][104] bf16 (cols
//         72..103 zero), Vt [64][80][512] bf16 (row 72 = ones).
// attn:   flash-style, no running max (R3 version, TK=64), denominator =
//         PV ones-column, XOR-swizzled lv, balanced 512-block grid.
// ---------------------------------------------------------------------------

typedef short bf16x8 __attribute__((ext_vector_type(8)));
typedef float f32x4 __attribute__((ext_vector_type(4)));

#define DEVI __device__ __forceinline__

DEVI unsigned f2bf(float f) {  // fp32 -> bf16 RNE (low 16 of result)
  unsigned u = __builtin_bit_cast(unsigned, f);
  return (u + 0x7fffu + ((u >> 16) & 1u)) >> 16;
}
DEVI unsigned pk2(float a, float b) { return f2bf(a) | (f2bf(b) << 16); }

DEVI void async16(void* lds, const void* g) {  // global->LDS, lane*16B
  __builtin_amdgcn_global_load_lds(
      (const __attribute__((address_space(1))) unsigned int*)g,
      (__attribute__((address_space(3))) unsigned int*)lds, 16, 0, 0);
}

// ---------------------------------------------------------------- cast_w ----
__global__ __launch_bounds__(256) void cast_w_k(const float* __restrict__ Wk,
                                                const float* __restrict__ Wq,
                                                const float* __restrict__ Wv,
                                                unsigned short* __restrict__ wbt) {
  __shared__ float ldsT[72][65];
  const int mat = blockIdx.x / 12, kc = blockIdx.x % 12;
  const float* W = (mat == 0) ? Wk : (mat == 1) ? Wq : Wv;
  const float sc = (mat == 1) ? 0.11785113019775793f : 1.0f;  // 72^-0.5 in q
  const float* src = W + kc * 64 * 72;
  for (int i = threadIdx.x; i < 1152; i += 256) {
    float4 d = *(const float4*)(src + i * 4);
    int e = i * 4;
    ldsT[e % 72][e / 72] = d.x;
    ldsT[(e + 1) % 72][(e + 1) / 72] = d.y;
    ldsT[(e + 2) % 72][(e + 2) / 72] = d.z;
    ldsT[(e + 3) % 72][(e + 3) / 72] = d.w;
  }
  __syncthreads();
  for (int c = threadIdx.x; c < 640; c += 256) {
    int h = c >> 3, kb = (c & 7) * 8;
    uint4 o = {0u, 0u, 0u, 0u};
    if (h < 72) {
      const float* rowp = &ldsT[h][kb];
      o.x = pk2(rowp[0] * sc, rowp[1] * sc);
      o.y = pk2(rowp[2] * sc, rowp[3] * sc);
      o.z = pk2(rowp[4] * sc, rowp[5] * sc);
      o.w = pk2(rowp[6] * sc, rowp[7] * sc);
    }
    *(uint4*)(wbt + ((size_t)mat * 80 + h) * 768 + kc * 64 + kb) = o;
  }
}

// ------------------------------------------------------------------ proj ----
// grid 512, 256 thr / 4 waves, 2 blocks/CU (38 KB LDS). M=64, N=240, BK=64.
// Waves 2x2: mg = wave>>1 owns 32 rows, ng = wave&1 owns 8 (or 7) N-tiles.
// Per ks: 2 A + 8 B ds_read_b128 -> 16 MFMA (ratio 1.6).
struct ProjSmem {
  union {
    struct { short x[64 * 64]; short w[240 * 64]; } s;  // 8 KB + 30 KB
    short t[80 * 72];                                   // V-transpose
  };
};

__global__ __launch_bounds__(256, 2) void proj_k(
    const float* __restrict__ x, const unsigned short* __restrict__ wbt,
    unsigned short* __restrict__ Kg, unsigned short* __restrict__ Qg,
    unsigned short* __restrict__ Vt) {
  __shared__ __align__(16) ProjSmem sm;
  const int row0 = blockIdx.x * 64;
  const int tid = threadIdx.x, wave = tid >> 6, lane = tid & 63;
  const int quad = lane >> 4, l16 = lane & 15;
  const int lrow = lane >> 3, lcb = lane & 7;
  const int mg = wave >> 1, ng = wave & 1;
  const int ntile0 = ng * 8, ntn = ng ? 7 : 8;

  f32x4 acc[2][8] = {};  // [mt][j]; ng==1 uses j<7

  for (int k0 = 0; k0 < 768; k0 += 64) {
    // W tile [240][64], async16, source col-block swizzled
#pragma unroll
    for (int i = 0; i < 8; ++i) {
      int inst = i * 4 + wave;
      if (inst < 30) {
        int r = inst * 8 + lrow;
        async16(&sm.s.w[inst * 512], wbt + (size_t)r * 768 + k0 + (lcb ^ lrow) * 8);
      }
    }
    // x tile [64][64]: fp32 load -> bf16 -> swizzled ds_write_b128
#pragma unroll
    for (int i = 0; i < 2; ++i) {
      int task = tid + 256 * i;  // 512 = 64 rows x 8 col-blocks
      int row = task >> 3, cb = task & 7;
      const float* g = x + (size_t)(row0 + row) * 768 + k0 + cb * 8;
      float4 a = *(const float4*)g;
      float4 c = *(const float4*)(g + 4);
      uint4 o = {pk2(a.x, a.y), pk2(a.z, a.w), pk2(c.x, c.y), pk2(c.z, c.w)};
      *(uint4*)&sm.s.x[row * 64 + ((cb ^ (row & 7)) * 8)] = o;
    }
    __syncthreads();
#pragma unroll
    for (int ks = 0; ks < 2; ++ks) {
      const int pblk = ((ks << 2) | quad) ^ (l16 & 7);
      bf16x8 af[2];
#pragma unroll
      for (int mt = 0; mt < 2; ++mt)
        af[mt] = *(const bf16x8*)&sm.s.x[(mg * 32 + mt * 16 + l16) * 64 + pblk * 8];
#pragma unroll
      for (int j = 0; j < 8; ++j)
        if (j < ntn) {
          int nt = ntile0 + j;
          bf16x8 bf = *(const bf16x8*)&sm.s.w[(nt * 16 + l16) * 64 + pblk * 8];
          acc[0][j] = __builtin_amdgcn_mfma_f32_16x16x32_bf16(af[0], bf, acc[0][j], 0, 0, 0);
          acc[1][j] = __builtin_amdgcn_mfma_f32_16x16x32_bf16(af[1], bf, acc[1][j], 0, 0, 0);
        }
    }
    __syncthreads();
  }

  // epilogue: K tiles nt 0..4, Q tiles 5..9 (rows of 104, pad 72..103 zero),
  // V tiles 10..14 via LDS transpose.
#pragma unroll
  for (int mt = 0; mt < 2; ++mt)
#pragma unroll
    for (int r = 0; r < 4; ++r) {
      int lrow64 = mg * 32 + mt * 16 + quad * 4 + r;
      size_t grow = (size_t)row0 + lrow64;
#pragma unroll
      for (int j = 0; j < 8; ++j)
        if (j < ntn) {
          int nt = ntile0 + j;
          float v = acc[mt][j][r];
          if (nt < 5) {
            Kg[grow * 104 + nt * 16 + l16] = (unsigned short)f2bf(v);
          } else if (nt < 10) {
            Qg[grow * 104 + (nt - 5) * 16 + l16] = (unsigned short)f2bf(v);
          } else {
            sm.t[((nt - 10) * 16 + l16) * 72 + lrow64] = (short)f2bf(v);
          }
        }
      // pad zeroing: ng0 waves zero Kg, ng1 waves zero Qg (all rows covered)
      unsigned short* p = (ng ? Qg : Kg) + grow * 104;
      p[80 + l16] = 0;
      if (l16 < 8) p[96 + l16] = 0;
    }
  __syncthreads();
  int b = blockIdx.x >> 3, t0 = (blockIdx.x & 7) * 64;
  const uint4 ones = {0x3F803F80u, 0x3F803F80u, 0x3F803F80u, 0x3F803F80u};
  for (int c = tid; c < 640; c += 256) {
    int hr = c >> 3, tc = (c & 7) * 8;
    uint4 d = *(const uint4*)&sm.t[hr * 72 + tc];
    if (hr == 72) d = ones;
    *(uint4*)(Vt + ((size_t)b * 80 + hr) * 512 + t0 + tc) = d;
  }
}

// ------------------------------------------------------------------ attn ----
// R3 version: 512 blocks (balance-permuted), 4 waves, 16 Q-rows/wave, TK=64.
__global__ __launch_bounds__(256, 4) void attn_k(
    const unsigned short* __restrict__ Qg, const unsigned short* __restrict__ Kg,
    const unsigned short* __restrict__ Vt, float* __restrict__ out) {
  __shared__ __align__(16) short lk[64 * 104];    // stride 104: 2-way free
  __shared__ __align__(16) short lv[80 * 64];     // stride 64 + XOR swizzle
  __shared__ __align__(16) short lp[4][16 * 72];  // per-wave P, stride 72

  int idx = (blockIdx.x < 256) ? blockIdx.x : 767 - blockIdx.x;
  const int qb = 7 - (idx >> 6), b = idx & 63;
  const int tid = threadIdx.x, wave = tid >> 6, lane = tid & 63;
  const int quad = lane >> 4, l16 = lane & 15;
  const int lrow = lane >> 3, lcb = lane & 7;
  const int trow0 = qb * 64 + wave * 16;

  bf16x8 qf[3];
#pragma unroll
  for (int kt = 0; kt < 3; ++kt)
    qf[kt] = *(const bf16x8*)(Qg + ((size_t)b * 512 + trow0 + l16) * 104 + kt * 32 + quad * 8);

  f32x4 o[5] = {};

  for (int kb = 0; kb <= qb; ++kb) {
    const int s0 = kb * 64;
    const bool diag = (kb == qb);
    const int nact = diag ? (wave + 1) : 4;

#pragma unroll
    for (int j = 0; j < 4; ++j) {  // K tile: 64 x 104 = 13 KiB linear
      int inst = j * 4 + wave;
      if (inst < 13)
        async16(&lk[inst * 512], Kg + ((size_t)b * 512 + s0) * 104 + inst * 512 + lane * 8);
    }
    for (int j = wave; j < 10; j += 4) {  // V^T tile, swizzled source
      int r = j * 8 + lrow;
      async16(&lv[j * 512], Vt + ((size_t)b * 80 + r) * 512 + s0 + (lcb ^ lrow) * 8);
    }
    __syncthreads();

    f32x4 sacc[4] = {};
#pragma unroll
    for (int kt = 0; kt < 3; ++kt)
      for (int nt = 0; nt < nact; ++nt) {
        bf16x8 kf = *(const bf16x8*)&lk[(nt * 16 + l16) * 104 + kt * 32 + quad * 8];
        sacc[nt] = __builtin_amdgcn_mfma_f32_16x16x32_bf16(qf[kt], kf, sacc[nt], 0, 0, 0);
      }
    if (diag) {  // mask the straddling tile nt == wave
      int nt = wave;
#pragma unroll
      for (int r = 0; r < 4; ++r) {
        int t = trow0 + quad * 4 + r;
        if (s0 + nt * 16 + l16 > t) sacc[nt][r] = -1e30f;
      }
    }
    // p = exp(s) (no max subtraction), write to per-wave LDS in A-layout
#pragma unroll
    for (int nt = 0; nt < 4; ++nt)
#pragma unroll
      for (int r = 0; r < 4; ++r) {
        float p = (nt < nact) ? __expf(sacc[nt][r]) : 0.0f;
        lp[wave][(quad * 4 + r) * 72 + nt * 16 + l16] = (short)f2bf(p);
      }
    // O += P V^ (column 72 of V^ is ones -> denominator in o[4])
#pragma unroll
    for (int ks = 0; ks < 2; ++ks) {
      bf16x8 pf = *(const bf16x8*)&lp[wave][l16 * 72 + ks * 32 + quad * 8];
      const int pblk = ((ks << 2) | quad) ^ (l16 & 7);
#pragma unroll
      for (int nt = 0; nt < 5; ++nt) {
        bf16x8 vf = *(const bf16x8*)&lv[(nt * 16 + l16) * 64 + pblk * 8];
        o[nt] = __builtin_amdgcn_mfma_f32_16x16x32_bf16(pf, vf, o[nt], 0, 0, 0);
      }
    }
    __syncthreads();
  }

#pragma unroll
  for (int r = 0; r < 4; ++r) {
    float l = __shfl(o[4][r], (lane & 48) | 8, 64);
    float inv = 1.0f / l;
    size_t t = (size_t)b * 512 + trow0 + quad * 4 + r;
#pragma unroll
    for (int nt = 0; nt < 5; ++nt) {
      int h = nt * 16 + l16;
      if (h < 72) out[t * 72 + h] = o[nt][r] * inv;
    }
  }
}

// ---------------------------------------------------------------------------
extern "C" void kernel_launch(void* const* d_in, const int* in_sizes, int n_in,
                              void* d_out, int out_size, void* d_ws, size_t ws_size,
                              hipStream_t stream) {
  const float* x  = (const float*)d_in[0];
  const float* Wk = (const float*)d_in[1];
  const float* Wq = (const float*)d_in[2];
  const float* Wv = (const float*)d_in[3];
  float* out = (float*)d_out;

  char* ws = (char*)d_ws;
  unsigned short* Kg  = (unsigned short*)(ws);             // 6,815,744
  unsigned short* Qg  = (unsigned short*)(ws + 6815744);   // 6,815,744
  unsigned short* Vt  = (unsigned short*)(ws + 13631488);  // 5,242,880
  unsigned short* wbt = (unsigned short*)(ws + 18874368);  //   368,640

  cast_w_k<<<36, 256, 0, stream>>>(Wk, Wq, Wv, wbt);
  proj_k<<<512, 256, 0, stream>>>(x, wbt, Kg, Qg, Vt);
  attn_k<<<512, 256, 0, stream>>>(Qg, Kg, Vt, out);
}

// Round 7
// 189.209 us; speedup vs baseline: 1.0877x; 1.0199x over previous
//
#include <hip/hip_runtime.h>

// ---------------------------------------------------------------------------
// Causal single-head attention, B=64 T=512 C=768 H=72, fp32 in/out.
// cast_w: W -> wbt bf16 [3][80][768] (transposed, padded, Wq pre-scaled)
// proj:   fused QKV GEMM, M=64 grid 512 (2 blocks/CU), BK=128, waves 2x2;
//         x loaded NON-TEMPORAL (keeps W L2-resident) and cast in staging.
//         Qg/Kg [32768][104] bf16 (cols 72..103 zero), Vt [64][80][512]
//         bf16 (row 72 = ones).
// attn:   flash-style, no running max (R3 version, TK=64), denominator =
//         PV ones-column, XOR-swizzled lv, balanced 512-block grid.
// ---------------------------------------------------------------------------

typedef short bf16x8 __attribute__((ext_vector_type(8)));
typedef float f32x4 __attribute__((ext_vector_type(4)));
typedef float f32x4v __attribute__((ext_vector_type(4)));

#define DEVI __device__ __forceinline__

DEVI unsigned f2bf(float f) {  // fp32 -> bf16 RNE (low 16 of result)
  unsigned u = __builtin_bit_cast(unsigned, f);
  return (u + 0x7fffu + ((u >> 16) & 1u)) >> 16;
}
DEVI unsigned pk2(float a, float b) { return f2bf(a) | (f2bf(b) << 16); }

DEVI void async16(void* lds, const void* g) {  // global->LDS, lane*16B
  __builtin_amdgcn_global_load_lds(
      (const __attribute__((address_space(1))) unsigned int*)g,
      (__attribute__((address_space(3))) unsigned int*)lds, 16, 0, 0);
}

// ---------------------------------------------------------------- cast_w ----
__global__ __launch_bounds__(256) void cast_w_k(const float* __restrict__ Wk,
                                                const float* __restrict__ Wq,
                                                const float* __restrict__ Wv,
                                                unsigned short* __restrict__ wbt) {
  __shared__ float ldsT[72][65];
  const int mat = blockIdx.x / 12, kc = blockIdx.x % 12;
  const float* W = (mat == 0) ? Wk : (mat == 1) ? Wq : Wv;
  const float sc = (mat == 1) ? 0.11785113019775793f : 1.0f;  // 72^-0.5 in q
  const float* src = W + kc * 64 * 72;
  for (int i = threadIdx.x; i < 1152; i += 256) {
    float4 d = *(const float4*)(src + i * 4);
    int e = i * 4;
    ldsT[e % 72][e / 72] = d.x;
    ldsT[(e + 1) % 72][(e + 1) / 72] = d.y;
    ldsT[(e + 2) % 72][(e + 2) / 72] = d.z;
    ldsT[(e + 3) % 72][(e + 3) / 72] = d.w;
  }
  __syncthreads();
  for (int c = threadIdx.x; c < 640; c += 256) {
    int h = c >> 3, kb = (c & 7) * 8;
    uint4 o = {0u, 0u, 0u, 0u};
    if (h < 72) {
      const float* rowp = &ldsT[h][kb];
      o.x = pk2(rowp[0] * sc, rowp[1] * sc);
      o.y = pk2(rowp[2] * sc, rowp[3] * sc);
      o.z = pk2(rowp[4] * sc, rowp[5] * sc);
      o.w = pk2(rowp[6] * sc, rowp[7] * sc);
    }
    *(uint4*)(wbt + ((size_t)mat * 80 + h) * 768 + kc * 64 + kb) = o;
  }
}

// ------------------------------------------------------------------ proj ----
// grid 512, 256 thr / 4 waves, 2 blocks/CU (76 KB LDS). M=64, N=240, BK=128.
// Waves 2x2 over (M,N): mg owns 32 rows, ng owns 8 (or 7) N-tiles.
// Per K-iter per wave: 64 MFMA / 40 ds_read_b128.
struct ProjSmem {
  union {
    struct { short x[64 * 128]; short w[240 * 128]; } s;  // 16 KB + 60 KB
    short t[80 * 72];                                     // V-transpose
  };
};

__global__ __launch_bounds__(256, 2) void proj_k(
    const float* __restrict__ x, const unsigned short* __restrict__ wbt,
    unsigned short* __restrict__ Kg, unsigned short* __restrict__ Qg,
    unsigned short* __restrict__ Vt) {
  __shared__ __align__(16) ProjSmem sm;
  const int row0 = blockIdx.x * 64;
  const int tid = threadIdx.x, wave = tid >> 6, lane = tid & 63;
  const int quad = lane >> 4, l16 = lane & 15;
  const int mg = wave >> 1, ng = wave & 1;
  const int ntile0 = ng * 8, ntn = ng ? 7 : 8;

  f32x4 acc[2][8] = {};  // [mt][j]; ng==1 uses j<7

  for (int k0 = 0; k0 < 768; k0 += 128) {
    // 1) x loads FIRST, non-temporal (don't evict W from L2).
    //    1024 tasks = 64 rows x 16 col-blocks of 8; 4 tasks/thread.
    f32x4v xa[4], xb_[4];
    int trow[4], tcb[4];
#pragma unroll
    for (int i = 0; i < 4; ++i) {
      int task = tid + 256 * i;
      trow[i] = task >> 4;
      tcb[i] = task & 15;
      const float* g = x + (size_t)(row0 + trow[i]) * 768 + k0 + tcb[i] * 8;
      xa[i] = __builtin_nontemporal_load((const f32x4v*)g);
      xb_[i] = __builtin_nontemporal_load((const f32x4v*)(g + 4));
    }
    // 2) W tile [240][128] via async16 (1 inst = 4 rows), source swizzled.
#pragma unroll
    for (int j = 0; j < 15; ++j) {
      int inst = j * 4 + wave;  // 0..59
      int r = inst * 4 + (lane >> 4);
      int cb = lane & 15;
      async16(&sm.s.w[inst * 512],
              wbt + (size_t)r * 768 + k0 + ((cb ^ (r & 15)) * 8));
    }
    // 3) pack x -> bf16, swizzled ds_write_b128.
#pragma unroll
    for (int i = 0; i < 4; ++i) {
      uint4 o = {pk2(xa[i].x, xa[i].y), pk2(xa[i].z, xa[i].w),
                 pk2(xb_[i].x, xb_[i].y), pk2(xb_[i].z, xb_[i].w)};
      *(uint4*)&sm.s.x[trow[i] * 128 + ((tcb[i] ^ (trow[i] & 15)) * 8)] = o;
    }
    __syncthreads();
#pragma unroll
    for (int ks = 0; ks < 4; ++ks) {
      const int pblk = ((ks << 2) | quad) ^ l16;  // 16-block XOR swizzle
      bf16x8 af[2];
#pragma unroll
      for (int mt = 0; mt < 2; ++mt)
        af[mt] = *(const bf16x8*)&sm.s.x[(mg * 32 + mt * 16 + l16) * 128 + pblk * 8];
#pragma unroll
      for (int j = 0; j < 8; ++j)
        if (j < ntn) {
          int nt = ntile0 + j;
          bf16x8 bf = *(const bf16x8*)&sm.s.w[(nt * 16 + l16) * 128 + pblk * 8];
          acc[0][j] = __builtin_amdgcn_mfma_f32_16x16x32_bf16(af[0], bf, acc[0][j], 0, 0, 0);
          acc[1][j] = __builtin_amdgcn_mfma_f32_16x16x32_bf16(af[1], bf, acc[1][j], 0, 0, 0);
        }
    }
    __syncthreads();
  }

  // epilogue: K tiles nt 0..4, Q tiles 5..9 (rows of 104, pad 72..103 zero),
  // V tiles 10..14 via LDS transpose.
#pragma unroll
  for (int mt = 0; mt < 2; ++mt)
#pragma unroll
    for (int r = 0; r < 4; ++r) {
      int lrow64 = mg * 32 + mt * 16 + quad * 4 + r;
      size_t grow = (size_t)row0 + lrow64;
#pragma unroll
      for (int j = 0; j < 8; ++j)
        if (j < ntn) {
          int nt = ntile0 + j;
          float v = acc[mt][j][r];
          if (nt < 5) {
            Kg[grow * 104 + nt * 16 + l16] = (unsigned short)f2bf(v);
          } else if (nt < 10) {
            Qg[grow * 104 + (nt - 5) * 16 + l16] = (unsigned short)f2bf(v);
          } else {
            sm.t[((nt - 10) * 16 + l16) * 72 + lrow64] = (short)f2bf(v);
          }
        }
      unsigned short* p = (ng ? Qg : Kg) + grow * 104;
      p[80 + l16] = 0;
      if (l16 < 8) p[96 + l16] = 0;
    }
  __syncthreads();
  int b = blockIdx.x >> 3, t0 = (blockIdx.x & 7) * 64;
  const uint4 ones = {0x3F803F80u, 0x3F803F80u, 0x3F803F80u, 0x3F803F80u};
  for (int c = tid; c < 640; c += 256) {
    int hr = c >> 3, tc = (c & 7) * 8;
    uint4 d = *(const uint4*)&sm.t[hr * 72 + tc];
    if (hr == 72) d = ones;
    *(uint4*)(Vt + ((size_t)b * 80 + hr) * 512 + t0 + tc) = d;
  }
}

// ------------------------------------------------------------------ attn ----
// R3 version: 512 blocks (balance-permuted), 4 waves, 16 Q-rows/wave, TK=64.
__global__ __launch_bounds__(256, 4) void attn_k(
    const unsigned short* __restrict__ Qg, const unsigned short* __restrict__ Kg,
    const unsigned short* __restrict__ Vt, float* __restrict__ out) {
  __shared__ __align__(16) short lk[64 * 104];    // stride 104: 2-way free
  __shared__ __align__(16) short lv[80 * 64];     // stride 64 + XOR swizzle
  __shared__ __align__(16) short lp[4][16 * 72];  // per-wave P, stride 72

  int idx = (blockIdx.x < 256) ? blockIdx.x : 767 - blockIdx.x;
  const int qb = 7 - (idx >> 6), b = idx & 63;
  const int tid = threadIdx.x, wave = tid >> 6, lane = tid & 63;
  const int quad = lane >> 4, l16 = lane & 15;
  const int lrow = lane >> 3, lcb = lane & 7;
  const int trow0 = qb * 64 + wave * 16;

  bf16x8 qf[3];
#pragma unroll
  for (int kt = 0; kt < 3; ++kt)
    qf[kt] = *(const bf16x8*)(Qg + ((size_t)b * 512 + trow0 + l16) * 104 + kt * 32 + quad * 8);

  f32x4 o[5] = {};

  for (int kb = 0; kb <= qb; ++kb) {
    const int s0 = kb * 64;
    const bool diag = (kb == qb);
    const int nact = diag ? (wave + 1) : 4;

#pragma unroll
    for (int j = 0; j < 4; ++j) {  // K tile: 64 x 104 = 13 KiB linear
      int inst = j * 4 + wave;
      if (inst < 13)
        async16(&lk[inst * 512], Kg + ((size_t)b * 512 + s0) * 104 + inst * 512 + lane * 8);
    }
    for (int j = wave; j < 10; j += 4) {  // V^T tile, swizzled source
      int r = j * 8 + lrow;
      async16(&lv[j * 512], Vt + ((size_t)b * 80 + r) * 512 + s0 + (lcb ^ lrow) * 8);
    }
    __syncthreads();

    f32x4 sacc[4] = {};
#pragma unroll
    for (int kt = 0; kt < 3; ++kt)
      for (int nt = 0; nt < nact; ++nt) {
        bf16x8 kf = *(const bf16x8*)&lk[(nt * 16 + l16) * 104 + kt * 32 + quad * 8];
        sacc[nt] = __builtin_amdgcn_mfma_f32_16x16x32_bf16(qf[kt], kf, sacc[nt], 0, 0, 0);
      }
    if (diag) {  // mask the straddling tile nt == wave
      int nt = wave;
#pragma unroll
      for (int r = 0; r < 4; ++r) {
        int t = trow0 + quad * 4 + r;
        if (s0 + nt * 16 + l16 > t) sacc[nt][r] = -1e30f;
      }
    }
    // p = exp(s) (no max subtraction), write to per-wave LDS in A-layout
#pragma unroll
    for (int nt = 0; nt < 4; ++nt)
#pragma unroll
      for (int r = 0; r < 4; ++r) {
        float p = (nt < nact) ? __expf(sacc[nt][r]) : 0.0f;
        lp[wave][(quad * 4 + r) * 72 + nt * 16 + l16] = (short)f2bf(p);
      }
    // O += P V^ (column 72 of V^ is ones -> denominator in o[4])
#pragma unroll
    for (int ks = 0; ks < 2; ++ks) {
      bf16x8 pf = *(const bf16x8*)&lp[wave][l16 * 72 + ks * 32 + quad * 8];
      const int pblk = ((ks << 2) | quad) ^ (l16 & 7);
#pragma unroll
      for (int nt = 0; nt < 5; ++nt) {
        bf16x8 vf = *(const bf16x8*)&lv[(nt * 16 + l16) * 64 + pblk * 8];
        o[nt] = __builtin_amdgcn_mfma_f32_16x16x32_bf16(pf, vf, o[nt], 0, 0, 0);
      }
    }
    __syncthreads();
  }

#pragma unroll
  for (int r = 0; r < 4; ++r) {
    float l = __shfl(o[4][r], (lane & 48) | 8, 64);
    float inv = 1.0f / l;
    size_t t = (size_t)b * 512 + trow0 + quad * 4 + r;
#pragma unroll
    for (int nt = 0; nt < 5; ++nt) {
      int h = nt * 16 + l16;
      if (h < 72) out[t * 72 + h] = o[nt][r] * inv;
    }
  }
}

// ---------------------------------------------------------------------------
extern "C" void kernel_launch(void* const* d_in, const int* in_sizes, int n_in,
                              void* d_out, int out_size, void* d_ws, size_t ws_size,
                              hipStream_t stream) {
  const float* x  = (const float*)d_in[0];
  const float* Wk = (const float*)d_in[1];
  const float* Wq = (const float*)d_in[2];
  const float* Wv = (const float*)d_in[3];
  float* out = (float*)d_out;

  char* ws = (char*)d_ws;
  unsigned short* Kg  = (unsigned short*)(ws);             // 6,815,744
  unsigned short* Qg  = (unsigned short*)(ws + 6815744);   // 6,815,744
  unsigned short* Vt  = (unsigned short*)(ws + 13631488);  // 5,242,880
  unsigned short* wbt = (unsigned short*)(ws + 18874368);  //   368,640

  cast_w_k<<<36, 256, 0, stream>>>(Wk, Wq, Wv, wbt);
  proj_k<<<512, 256, 0, stream>>>(x, wbt, Kg, Qg, Vt);
  attn_k<<<512, 256, 0, stream>>>(Qg, Kg, Vt, out);
}